// Round 2
// baseline (378.128 us; speedup 1.0000x reference)
//
#include <hip/hip_runtime.h>
#include <hip/hip_bf16.h>

typedef unsigned char u8;
typedef unsigned short u16;
typedef unsigned int u32;
typedef unsigned long long u64;

#define PP     254016   // 504*504
#define NPIX   2032128  // 8*PP
#define NTRIP  4913     // 17^3
#define N_F    2032128.0
#define RROWS  8        // output rows per block strip; 504 = 8*63
#define NRB    63

__device__ __forceinline__ float bf2f(__hip_bfloat16 h){ return __bfloat162float(h); }
__device__ __forceinline__ u32 f2bf(float f){
  u32 u = __float_as_uint(f);
  return ((u + 0x7FFFu + ((u >> 16) & 1u)) >> 16);   // RNE
}
// dual-dtype load: flag==1 -> float32, flag==0 -> bf16
__device__ __forceinline__ float ldv(const void* p, int i, u32 f){
  return f ? ((const float*)p)[i] : bf2f(((const __hip_bfloat16*)p)[i]);
}

typedef unsigned short us2 __attribute__((ext_vector_type(2)));
__device__ __forceinline__ u32 pkmax(u32 a, u32 b){
  us2 x = __builtin_bit_cast(us2, a);
  us2 y = __builtin_bit_cast(us2, b);
  us2 r = __builtin_elementwise_max(x, y);
  return __builtin_bit_cast(u32, r);
}

// padded-coord bin: 0 on the 1-ring pad, else round(x*255/16) in [0,16]
__device__ __forceinline__ u32 getbin(const void* x, u32 f, int img, int ch, int pr, int pc){
  if ((u32)(pr-1) < 512u && (u32)(pc-1) < 512u){
    float xv = ldv(x, ((img*3+ch)*512 + (pr-1))*512 + (pc-1), f);
    return (u32)(int)rintf(xv * 255.0f * 0.0625f);
  }
  return 0u;
}
__device__ __forceinline__ u64 bdelta(u32 b){ return (b < 16u) ? (1ull << (b*4)) : 0ull; }

// ---------------- K0: dtype detect + hist/sums zero (1 block) ----------------
__global__ __launch_bounds__(256) void k_init(const u16* __restrict__ xw, u32* __restrict__ flag,
                                              u32* __restrict__ hist, u32* __restrict__ s2){
  int t = threadIdx.x;
  for (int i=t; i<NTRIP; i+=256) hist[i] = 0u;
  if (t < 128) s2[t] = 0u;   // 64 doubles
  if (t < 64){
    u32 bad = 0;
    for (int i=t; i<1024; i+=64) bad |= (u32)(xw[i] >> 15);
    int anybad = __any((int)bad);
    if (t == 0) *flag = anybad ? 1u : 0u;
  }
}

// ---------------- K1: fused bins + 11x11 mode + triple + histogram ----------------
// Block = (image, 8-row strip). All 3 channels. Vertical counts: nibble-packed u64
// per column in LDS (bins 0..15; bin16 = 121 - sum). Register nibble-ring remembers
// the last 11 bins per owned column so row-removal needs no global re-read.
// Nibble-packed layout (8 B/col/ch) keeps the LDS pipe (~3.2K cyc/iter/CU) balanced
// against the expansion VALU (~3.1K cyc/iter/SIMD) -- byte-expanded LDS was tried
// and is LDS-bound (2x traffic on the narrower pipe).
__global__ __launch_bounds__(512) void k_fused(const void* __restrict__ x, const u32* __restrict__ flag,
                                               u16* __restrict__ triple, u32* __restrict__ hist){
  u32 f = *flag;
  int img = blockIdx.y;
  int r0 = blockIdx.x * RROWS;
  int t = threadIdx.x;
  __shared__ u64 CNT[3][518];
  __shared__ u32 lh[NTRIP];
  for (int i=t; i<NTRIP; i+=512) lh[i] = 0u;

  bool extra = (t < 2);
  int colB = 512 + t;
  u64 v[3] = {0,0,0}, vb[3] = {0,0,0};
  u64 rn[3] = {0,0,0}, rnb[3] = {0,0,0};
  u32 r16[3] = {0,0,0}, r16b[3] = {0,0,0};

  // prime: padded rows r0..r0+10
  for (int j=0; j<11; j++){
    int pr = r0 + j;
    #pragma unroll
    for (int ch=0; ch<3; ch++){
      u32 b = getbin(x, f, img, ch, pr, t);
      v[ch] += bdelta(b);
      rn[ch] = (rn[ch] << 4) | (u64)(b & 15u);
      r16[ch] = (r16[ch] << 1) | (b >> 4);
    }
    if (extra){
      #pragma unroll
      for (int ch=0; ch<3; ch++){
        u32 b = getbin(x, f, img, ch, pr, colB);
        vb[ch] += bdelta(b);
        rnb[ch] = (rnb[ch] << 4) | (u64)(b & 15u);
        r16b[ch] = (r16b[ch] << 1) | (b >> 4);
      }
    }
  }
  #pragma unroll
  for (int ch=0; ch<3; ch++) CNT[ch][t] = v[ch];
  if (extra){
    #pragma unroll
    for (int ch=0; ch<3; ch++) CNT[ch][colB] = vb[ch];
  }
  __syncthreads();

  for (int i=0; i<RROWS; i++){
    int r = r0 + i;
    if (t < 504){
      u32 m3[3];
      #pragma unroll
      for (int ch=0; ch<3; ch++){
        u64 he = 0, ho = 0;
        #pragma unroll
        for (int dx=0; dx<11; dx++){
          u64 n = CNT[ch][t+dx];
          he += n & 0x0F0F0F0F0F0F0F0Full;
          ho += (n >> 4) & 0x0F0F0F0F0F0F0F0Full;
        }
        u64 T = he + ho;                       // byte sums <= 242, no carry
        u32 T2 = (u32)T + (u32)(T >> 32);      // byte sums <= 242, no carry
        u32 s = (T2 & 0xFFu) + ((T2>>8)&0xFFu) + ((T2>>16)&0xFFu) + (T2>>24);
        u32 e_lo = (u32)he, e_hi = (u32)(he >> 32);
        u32 o_lo = (u32)ho, o_hi = (u32)(ho >> 32);
        u32 k0 = ((e_lo & 0x00FF00FFu) << 5) | 0x000C0010u;  // bins 0,4  -> idx 16,12
        u32 k1 = ((e_lo >> 3) & 0x1FE01FE0u) | 0x000A000Eu;  // bins 2,6  -> idx 14,10
        u32 k2 = ((e_hi & 0x00FF00FFu) << 5) | 0x00040008u;  // bins 8,12 -> idx 8,4
        u32 k3 = ((e_hi >> 3) & 0x1FE01FE0u) | 0x00020006u;  // bins 10,14-> idx 6,2
        u32 k4 = ((o_lo & 0x00FF00FFu) << 5) | 0x000B000Fu;  // bins 1,5  -> idx 15,11
        u32 k5 = ((o_lo >> 3) & 0x1FE01FE0u) | 0x0009000Du;  // bins 3,7  -> idx 13,9
        u32 k6 = ((o_hi & 0x00FF00FFu) << 5) | 0x00030007u;  // bins 9,13 -> idx 7,3
        u32 k7 = ((o_hi >> 3) & 0x1FE01FE0u) | 0x00010005u;  // bins 11,15-> idx 5,1
        u32 m = pkmax(pkmax(pkmax(k0,k1), pkmax(k2,k3)), pkmax(pkmax(k4,k5), pkmax(k6,k7)));
        u32 best = m >> 16, blo = m & 0xFFFFu;
        best = best > blo ? best : blo;
        u32 k16 = (121u - s) << 5;             // bin16: idx 0, loses all ties
        best = best > k16 ? best : k16;
        m3[ch] = 16u - (best & 31u);
      }
      u32 idx = (m3[0]*17u + m3[1])*17u + m3[2];
      triple[img*PP + r*504 + t] = (u16)idx;
      atomicAdd(&lh[idx], 1u);
    }
    __syncthreads();
    if (i+1 < RROWS){
      #pragma unroll
      for (int ch=0; ch<3; ch++){
        u32 nb = getbin(x, f, img, ch, r+11, t);
        rn[ch] = (rn[ch] << 4) | (u64)(nb & 15u);
        r16[ch] = (r16[ch] << 1) | (nb >> 4);
        u32 ob = (u32)((rn[ch] >> 44) & 15u);
        u32 o16 = (r16[ch] >> 11) & 1u;
        v[ch] += bdelta(nb);
        v[ch] -= o16 ? 0ull : (1ull << (ob*4));
        CNT[ch][t] = v[ch];
      }
      if (extra){
        #pragma unroll
        for (int ch=0; ch<3; ch++){
          u32 nb = getbin(x, f, img, ch, r+11, colB);
          rnb[ch] = (rnb[ch] << 4) | (u64)(nb & 15u);
          r16b[ch] = (r16b[ch] << 1) | (nb >> 4);
          u32 ob = (u32)((rnb[ch] >> 44) & 15u);
          u32 o16 = (r16b[ch] >> 11) & 1u;
          vb[ch] += bdelta(nb);
          vb[ch] -= o16 ? 0ull : (1ull << (ob*4));
          CNT[ch][colB] = vb[ch];
        }
      }
    }
    __syncthreads();
  }
  for (int i=t; i<NTRIP; i+=512){ u32 c = lh[i]; if (c) atomicAdd(&hist[i], c); }
}

// ---- shared device helper: 9 integer moments + stage-1 folded P1 (all 256 threads) ----
__device__ __forceinline__ void compute_P1(const u32* __restrict__ hist,
    const void* w1, const void* b1, const void* wd1, const void* bd1,
    const void* g1, const void* be1, u32 f, float* sP /*LDS[128]*/,
    u32* wred /*LDS[36]*/, u32* mom /*LDS[9]*/){
  u32 a0=0,a1=0,a2=0,a3=0,a4=0,a5=0,a6=0,a7=0,a8=0;
  for (int t=threadIdx.x; t<NTRIP; t+=256){
    u32 c = hist[t];
    int m2 = t % 17; int tt = t/17; int m1 = tt % 17; int m0 = tt/17;
    a0 += c*m0; a1 += c*m1; a2 += c*m2;
    a3 += c*m0*m0; a4 += c*m1*m1; a5 += c*m2*m2;
    a6 += c*m0*m1; a7 += c*m0*m2; a8 += c*m1*m2;
  }
  #pragma unroll
  for (int s=1; s<64; s<<=1){
    a0 += __shfl_xor(a0,s); a1 += __shfl_xor(a1,s); a2 += __shfl_xor(a2,s);
    a3 += __shfl_xor(a3,s); a4 += __shfl_xor(a4,s); a5 += __shfl_xor(a5,s);
    a6 += __shfl_xor(a6,s); a7 += __shfl_xor(a7,s); a8 += __shfl_xor(a8,s);
  }
  int wv = threadIdx.x >> 6;
  if ((threadIdx.x & 63) == 0){
    wred[wv*9+0]=a0; wred[wv*9+1]=a1; wred[wv*9+2]=a2; wred[wv*9+3]=a3; wred[wv*9+4]=a4;
    wred[wv*9+5]=a5; wred[wv*9+6]=a6; wred[wv*9+7]=a7; wred[wv*9+8]=a8;
  }
  __syncthreads();
  if (threadIdx.x < 9) mom[threadIdx.x] = wred[threadIdx.x] + wred[9+threadIdx.x] + wred[18+threadIdx.x] + wred[27+threadIdx.x];
  __syncthreads();
  if (threadIdx.x < 32){
    int o = threadIdx.x;
    double wd = ldv(wd1,o,f);
    double q0 = wd*ldv(w1,o*3+0,f), q1 = wd*ldv(w1,o*3+1,f), q2 = wd*ldv(w1,o*3+2,f);
    double qc = wd*ldv(b1,o,f) + ldv(bd1,o,f);
    double S0=mom[0],S1=mom[1],S2=mom[2],S00=mom[3],S11=mom[4],S22=mom[5],S01=mom[6],S02=mom[7],S12=mom[8];
    double lin = (q0*S0 + q1*S1 + q2*S2) * (1.0/16.0);
    double mean = lin/N_F + qc;
    double quad = (q0*q0*S00 + q1*q1*S11 + q2*q2*S22 + 2.0*(q0*q1*S01 + q0*q2*S02 + q1*q2*S12)) * (1.0/256.0);
    double Ev2 = quad/N_F + 2.0*qc*lin/N_F + qc*qc;
    double var = Ev2 - mean*mean;
    double rstd = 1.0 / sqrt(var + 1e-5);
    double A = rstd * ldv(g1,o,f);
    double B = ldv(be1,o,f) - mean*A;
    sP[o]      = (float)(q0*A);
    sP[32+o]   = (float)(q1*A);
    sP[64+o]   = (float)(q2*A);
    sP[96+o]   = (float)(qc*A + B);
  }
  __syncthreads();
}

// ---------------- K2: triple-parallel pre-BN LUT + stage-2 BN sums ----------------
// Thread = (triple-slot, out-channel). Writes v2 (pre-BN stage-2 value) per
// (triple, o) into lutpre; accumulates count-weighted sum / sum-of-squares per o,
// block-reduces, f64-atomicAdd into sums2[64].
__global__ __launch_bounds__(256) void k_stats(const u32* __restrict__ hist,
    const void* w1, const void* b1, const void* wd1, const void* bd1, const void* g1, const void* be1,
    const void* w2, const void* b2, const void* wd2, const void* bd2,
    float* __restrict__ lutpre, double* __restrict__ sums2, const u32* __restrict__ flag){
  u32 f = *flag;
  __shared__ float sP[128];
  __shared__ u32 wred[36], mom[9];
  __shared__ float sw[1024];
  __shared__ float swd[32], scc[32];
  compute_P1(hist, w1,b1,wd1,bd1,g1,be1, f, sP, wred, mom);
  for (int i=threadIdx.x;i<1024;i+=256) sw[i] = ldv(w2, i, f);
  if (threadIdx.x < 32){
    int o = threadIdx.x;
    float wd = ldv(wd2,o,f);
    swd[o] = wd;
    scc[o] = wd*ldv(b2,o,f) + ldv(bd2,o,f);
  }
  __syncthreads();
  int o = threadIdx.x & 31, slot = threadIdx.x >> 5;
  double s = 0.0, q = 0.0;
  for (int t = blockIdx.x*8 + slot; t < NTRIP; t += gridDim.x*8){
    int m2 = t % 17; int tt = t/17; int m1 = tt % 17; int m0 = tt/17;
    float f0 = m0*(1.f/16.f), f1 = m1*(1.f/16.f), f2v = m2*(1.f/16.f);
    float dot = 0.f;
    #pragma unroll
    for (int c=0;c<32;c++){
      float u = sP[c]*f0 + sP[32+c]*f1 + sP[64+c]*f2v + sP[96+c];
      float y = (u >= 0.f) ? u : 0.01f*u;
      dot += sw[o*32+c]*y;
    }
    float v2 = swd[o]*dot + scc[o];
    lutpre[t*32+o] = v2;
    double cn = (double)hist[t];
    s += cn*(double)v2;
    q += cn*(double)v2*(double)v2;
  }
  // combine the two slots sharing each wave, then across the 4 waves
  s += __shfl_xor(s, 32);
  q += __shfl_xor(q, 32);
  __shared__ double sred[2][4][32];
  int wv = threadIdx.x >> 6, ln = threadIdx.x & 63;
  if (ln < 32){ sred[0][wv][ln] = s; sred[1][wv][ln] = q; }
  __syncthreads();
  if (threadIdx.x < 32){
    int oo = threadIdx.x;
    double ss = sred[0][0][oo]+sred[0][1][oo]+sred[0][2][oo]+sred[0][3][oo];
    atomicAdd(&sums2[oo], ss);
  } else if (threadIdx.x < 64){
    int oo = threadIdx.x - 32;
    double qq = sred[1][0][oo]+sred[1][1][oo]+sred[1][2][oo]+sred[1][3][oo];
    atomicAdd(&sums2[32+oo], qq);
  }
}

// ---------------- K3: gather pre-BN LUT -> BN affine + LeakyReLU -> output ----------------
// k_out is write-bound (1.04 GB f32); the per-element BN affine + leaky runs on
// the otherwise-idle VALU. ka/kb computed per block from sums2 (trivial).
__global__ __launch_bounds__(256) void k_out(const u16* __restrict__ triple, const float* __restrict__ lutpre,
                                             const double* __restrict__ sums2,
                                             const void* g2, const void* be2,
                                             void* __restrict__ out, const u32* __restrict__ flag){
  u32 f = *flag;
  __shared__ float ka[32], kb[32];
  if (threadIdx.x < 32){
    int o = threadIdx.x;
    double mean = sums2[o] / N_F;
    double var  = sums2[32+o] / N_F - mean*mean;
    double rstd = 1.0 / sqrt(var + 1e-5);
    double A = rstd * (double)ldv(g2,o,f);
    double B = (double)ldv(be2,o,f) - mean*A;
    ka[o] = (float)A; kb[o] = (float)B;
  }
  __syncthreads();
  int g = blockIdx.x*256 + threadIdx.x;
  if (g >= NPIX/2) return;
  int p0 = g*2;
  int bimg = p0 / PP; int pix = p0 - bimg*PP;
  u32 tt = *(const u32*)(triple + p0);
  u32 ia = tt & 0xFFFFu, ib = tt >> 16;
  const float4* La = (const float4*)(lutpre + (size_t)ia*32);
  const float4* Lb = (const float4*)(lutpre + (size_t)ib*32);
  if (f){  // float32 output path
    float* ob = (float*)out + (size_t)bimg*32*PP + pix;
    #pragma unroll
    for (int j=0;j<8;j++){
      float4 a = La[j]; float4 b = Lb[j];
      float4 K = *(const float4*)&ka[4*j];
      float4 C = *(const float4*)&kb[4*j];
      float2 v;
      float ax, bx;
      ax = fmaf(a.x, K.x, C.x); ax = ax>=0.f?ax:0.01f*ax;
      bx = fmaf(b.x, K.x, C.x); bx = bx>=0.f?bx:0.01f*bx;
      v.x=ax; v.y=bx; *(float2*)(ob + (size_t)(4*j+0)*PP) = v;
      ax = fmaf(a.y, K.y, C.y); ax = ax>=0.f?ax:0.01f*ax;
      bx = fmaf(b.y, K.y, C.y); bx = bx>=0.f?bx:0.01f*bx;
      v.x=ax; v.y=bx; *(float2*)(ob + (size_t)(4*j+1)*PP) = v;
      ax = fmaf(a.z, K.z, C.z); ax = ax>=0.f?ax:0.01f*ax;
      bx = fmaf(b.z, K.z, C.z); bx = bx>=0.f?bx:0.01f*bx;
      v.x=ax; v.y=bx; *(float2*)(ob + (size_t)(4*j+2)*PP) = v;
      ax = fmaf(a.w, K.w, C.w); ax = ax>=0.f?ax:0.01f*ax;
      bx = fmaf(b.w, K.w, C.w); bx = bx>=0.f?bx:0.01f*bx;
      v.x=ax; v.y=bx; *(float2*)(ob + (size_t)(4*j+3)*PP) = v;
    }
  } else { // bf16 output: apply affine+leaky then RNE-pack pixel pairs
    u16* ob = (u16*)out + (size_t)bimg*32*PP + pix;
    #pragma unroll
    for (int j=0;j<8;j++){
      float4 a = La[j]; float4 b = Lb[j];
      float4 K = *(const float4*)&ka[4*j];
      float4 C = *(const float4*)&kb[4*j];
      float ax, bx;
      ax = fmaf(a.x, K.x, C.x); ax = ax>=0.f?ax:0.01f*ax;
      bx = fmaf(b.x, K.x, C.x); bx = bx>=0.f?bx:0.01f*bx;
      *(u32*)(ob + (size_t)(4*j+0)*PP) = f2bf(ax) | (f2bf(bx) << 16);
      ax = fmaf(a.y, K.y, C.y); ax = ax>=0.f?ax:0.01f*ax;
      bx = fmaf(b.y, K.y, C.y); bx = bx>=0.f?bx:0.01f*bx;
      *(u32*)(ob + (size_t)(4*j+1)*PP) = f2bf(ax) | (f2bf(bx) << 16);
      ax = fmaf(a.z, K.z, C.z); ax = ax>=0.f?ax:0.01f*ax;
      bx = fmaf(b.z, K.z, C.z); bx = bx>=0.f?bx:0.01f*bx;
      *(u32*)(ob + (size_t)(4*j+2)*PP) = f2bf(ax) | (f2bf(bx) << 16);
      ax = fmaf(a.w, K.w, C.w); ax = ax>=0.f?ax:0.01f*ax;
      bx = fmaf(b.w, K.w, C.w); bx = bx>=0.f?bx:0.01f*bx;
      *(u32*)(ob + (size_t)(4*j+3)*PP) = f2bf(ax) | (f2bf(bx) << 16);
    }
  }
}

extern "C" void kernel_launch(void* const* d_in, const int* in_sizes, int n_in,
                              void* d_out, int out_size, void* d_ws, size_t ws_size,
                              hipStream_t stream){
  const void* x   = d_in[0];
  const void* w1  = d_in[1];
  const void* b1  = d_in[2];
  const void* wd1 = d_in[3];
  const void* bd1 = d_in[4];
  const void* g1  = d_in[5];
  const void* be1 = d_in[6];
  const void* w2  = d_in[7];
  const void* b2  = d_in[8];
  const void* wd2 = d_in[9];
  const void* bd2 = d_in[10];
  const void* g2  = d_in[11];
  const void* be2 = d_in[12];

  char* w = (char*)d_ws;
  auto alloc = [&](size_t bytes)->char* { char* p = w; w += (bytes + 255) & ~(size_t)255; return p; };
  u32*    flag   = (u32*)   alloc(256);
  u16*    triple = (u16*)   alloc(2ull*NPIX);        // 4.06 MB
  u32*    hist   = (u32*)   alloc(4ull*NTRIP);
  double* sums2  = (double*)alloc(64ull*8);
  float*  lutpre = (float*) alloc(4ull*NTRIP*32);    // 629 KB

  k_init<<<dim3(1), 256, 0, stream>>>((const u16*)x, flag, hist, (u32*)sums2);
  k_fused<<<dim3(NRB, 8), 512, 0, stream>>>(x, flag, triple, hist);
  k_stats<<<dim3(256), 256, 0, stream>>>(hist, w1,b1,wd1,bd1,g1,be1, w2,b2,wd2,bd2,
                                         lutpre, sums2, flag);
  k_out<<<dim3((NPIX/2)/256), 256, 0, stream>>>(triple, lutpre, sums2, g2, be2, d_out, flag);
}

// Round 3
// 371.423 us; speedup vs baseline: 1.0181x; 1.0181x over previous
//
#include <hip/hip_runtime.h>
#include <hip/hip_bf16.h>

typedef unsigned char u8;
typedef unsigned short u16;
typedef unsigned int u32;
typedef unsigned long long u64;

#define PP     254016   // 504*504
#define NPIX   2032128  // 8*PP
#define NTRIP  4913     // 17^3
#define N_F    2032128.0
#define RROWS  8        // output rows per block strip; 504 = 8*63
#define NRB    63

__device__ __forceinline__ float bf2f(__hip_bfloat16 h){ return __bfloat162float(h); }
__device__ __forceinline__ u32 f2bf(float f){
  u32 u = __float_as_uint(f);
  return ((u + 0x7FFFu + ((u >> 16) & 1u)) >> 16);   // RNE
}
// dual-dtype load: flag==1 -> float32, flag==0 -> bf16
__device__ __forceinline__ float ldv(const void* p, int i, u32 f){
  return f ? ((const float*)p)[i] : bf2f(((const __hip_bfloat16*)p)[i]);
}

typedef unsigned short us2 __attribute__((ext_vector_type(2)));
__device__ __forceinline__ u32 pkmax(u32 a, u32 b){
  us2 x = __builtin_bit_cast(us2, a);
  us2 y = __builtin_bit_cast(us2, b);
  us2 r = __builtin_elementwise_max(x, y);
  return __builtin_bit_cast(u32, r);
}

// padded-coord bin: 0 on the 1-ring pad, else round(x*255/16) in [0,16]
__device__ __forceinline__ u32 getbin(const void* x, u32 f, int img, int ch, int pr, int pc){
  if ((u32)(pr-1) < 512u && (u32)(pc-1) < 512u){
    float xv = ldv(x, ((img*3+ch)*512 + (pr-1))*512 + (pc-1), f);
    return (u32)(int)rintf(xv * 255.0f * 0.0625f);
  }
  return 0u;
}
__device__ __forceinline__ u64 bdelta(u32 b){ return (b < 16u) ? (1ull << (b*4)) : 0ull; }

// ---------------- K0: dtype detect + hist/sums zero (1 block) ----------------
__global__ __launch_bounds__(256) void k_init(const u16* __restrict__ xw, u32* __restrict__ flag,
                                              u32* __restrict__ hist, u32* __restrict__ s2){
  int t = threadIdx.x;
  for (int i=t; i<NTRIP; i+=256) hist[i] = 0u;
  if (t < 128) s2[t] = 0u;   // 64 doubles
  if (t < 64){
    u32 bad = 0;
    for (int i=t; i<1024; i+=64) bad |= (u32)(xw[i] >> 15);
    int anybad = __any((int)bad);
    if (t == 0) *flag = anybad ? 1u : 0u;
  }
}

// ---------------- K1: fused bins + 11x11 mode + triple + histogram ----------------
// Block = (image, 8-row strip). All 3 channels. Vertical counts kept nibble-packed
// in registers (cheap ring update); written to LDS BYTE-EXPANDED as {even-bin
// bytes, odd-bin bytes} (contiguous-lane b128 = conflict-free; measured faster
// than nibble-packed LDS). Horizontal 11-window via shared pair-sums:
//   P2[c] = C[c]+C[c+1];  W11[c] = P2[c]+P2[c+2]+P2[c+4]+P2[c+6]+P2[c+8]+C[c+10]
// -> 6 LDS reads/px/ch instead of 11 (bit-identical he/ho; bytes <=121, no carry).
__global__ __launch_bounds__(512) void k_fused(const void* __restrict__ x, const u32* __restrict__ flag,
                                               u16* __restrict__ triple, u32* __restrict__ hist){
  u32 f = *flag;
  int img = blockIdx.y;
  int r0 = blockIdx.x * RROWS;
  int t = threadIdx.x;
  __shared__ ulonglong2 CNT[3][516];   // {he, ho} per padded column (byte-expanded)
  __shared__ ulonglong2 P2S[3][516];   // pair sums: CNT[c] + CNT[c+1]
  __shared__ u32 lh[NTRIP];
  for (int i=t; i<NTRIP; i+=512) lh[i] = 0u;

  const u64 M4 = 0x0F0F0F0F0F0F0F0Full;
  bool extra = (t < 2);
  int colB = 512 + t;
  u64 v[3] = {0,0,0}, vb[3] = {0,0,0};
  u64 rn[3] = {0,0,0}, rnb[3] = {0,0,0};
  u32 r16[3] = {0,0,0}, r16b[3] = {0,0,0};

  // prime: padded rows r0..r0+10
  for (int j=0; j<11; j++){
    int pr = r0 + j;
    #pragma unroll
    for (int ch=0; ch<3; ch++){
      u32 b = getbin(x, f, img, ch, pr, t);
      v[ch] += bdelta(b);
      rn[ch] = (rn[ch] << 4) | (u64)(b & 15u);
      r16[ch] = (r16[ch] << 1) | (b >> 4);
    }
    if (extra){
      #pragma unroll
      for (int ch=0; ch<3; ch++){
        u32 b = getbin(x, f, img, ch, pr, colB);
        vb[ch] += bdelta(b);
        rnb[ch] = (rnb[ch] << 4) | (u64)(b & 15u);
        r16b[ch] = (r16b[ch] << 1) | (b >> 4);
      }
    }
  }
  #pragma unroll
  for (int ch=0; ch<3; ch++){
    ulonglong2 e; e.x = v[ch] & M4; e.y = (v[ch] >> 4) & M4; CNT[ch][t] = e;
  }
  if (extra){
    #pragma unroll
    for (int ch=0; ch<3; ch++){
      ulonglong2 e; e.x = vb[ch] & M4; e.y = (vb[ch] >> 4) & M4; CNT[ch][colB] = e;
    }
  }
  __syncthreads();
  #pragma unroll
  for (int ch=0; ch<3; ch++){
    ulonglong2 a = CNT[ch][t], b = CNT[ch][t+1];
    ulonglong2 p; p.x = a.x + b.x; p.y = a.y + b.y;
    P2S[ch][t] = p;
  }
  __syncthreads();

  for (int i=0; i<RROWS; i++){
    int r = r0 + i;
    if (t < 504){
      u32 m3[3];
      #pragma unroll
      for (int ch=0; ch<3; ch++){
        ulonglong2 p0 = P2S[ch][t],   p1 = P2S[ch][t+2], p2 = P2S[ch][t+4];
        ulonglong2 p3 = P2S[ch][t+6], p4 = P2S[ch][t+8];
        ulonglong2 cl = CNT[ch][t+10];
        u64 he = p0.x + p1.x + p2.x + p3.x + p4.x + cl.x;
        u64 ho = p0.y + p1.y + p2.y + p3.y + p4.y + cl.y;
        u64 T = he + ho;                       // byte sums <= 242, no carry
        u32 T2 = (u32)T + (u32)(T >> 32);      // byte sums <= 242, no carry
        u32 s = (T2 & 0xFFu) + ((T2>>8)&0xFFu) + ((T2>>16)&0xFFu) + (T2>>24);
        u32 e_lo = (u32)he, e_hi = (u32)(he >> 32);
        u32 o_lo = (u32)ho, o_hi = (u32)(ho >> 32);
        u32 k0 = ((e_lo & 0x00FF00FFu) << 5) | 0x000C0010u;  // bins 0,4  -> idx 16,12
        u32 k1 = ((e_lo >> 3) & 0x1FE01FE0u) | 0x000A000Eu;  // bins 2,6  -> idx 14,10
        u32 k2 = ((e_hi & 0x00FF00FFu) << 5) | 0x00040008u;  // bins 8,12 -> idx 8,4
        u32 k3 = ((e_hi >> 3) & 0x1FE01FE0u) | 0x00020006u;  // bins 10,14-> idx 6,2
        u32 k4 = ((o_lo & 0x00FF00FFu) << 5) | 0x000B000Fu;  // bins 1,5  -> idx 15,11
        u32 k5 = ((o_lo >> 3) & 0x1FE01FE0u) | 0x0009000Du;  // bins 3,7  -> idx 13,9
        u32 k6 = ((o_hi & 0x00FF00FFu) << 5) | 0x00030007u;  // bins 9,13 -> idx 7,3
        u32 k7 = ((o_hi >> 3) & 0x1FE01FE0u) | 0x00010005u;  // bins 11,15-> idx 5,1
        u32 m = pkmax(pkmax(pkmax(k0,k1), pkmax(k2,k3)), pkmax(pkmax(k4,k5), pkmax(k6,k7)));
        u32 best = m >> 16, blo = m & 0xFFFFu;
        best = best > blo ? best : blo;
        u32 k16 = (121u - s) << 5;             // bin16: idx 0, loses all ties
        best = best > k16 ? best : k16;
        m3[ch] = 16u - (best & 31u);
      }
      u32 idx = (m3[0]*17u + m3[1])*17u + m3[2];
      triple[img*PP + r*504 + t] = (u16)idx;
      atomicAdd(&lh[idx], 1u);
    }
    __syncthreads();
    if (i+1 < RROWS){
      #pragma unroll
      for (int ch=0; ch<3; ch++){
        u32 nb = getbin(x, f, img, ch, r+11, t);
        rn[ch] = (rn[ch] << 4) | (u64)(nb & 15u);
        r16[ch] = (r16[ch] << 1) | (nb >> 4);
        u32 ob = (u32)((rn[ch] >> 44) & 15u);
        u32 o16 = (r16[ch] >> 11) & 1u;
        v[ch] += bdelta(nb);
        v[ch] -= o16 ? 0ull : (1ull << (ob*4));
        ulonglong2 e; e.x = v[ch] & M4; e.y = (v[ch] >> 4) & M4; CNT[ch][t] = e;
      }
      if (extra){
        #pragma unroll
        for (int ch=0; ch<3; ch++){
          u32 nb = getbin(x, f, img, ch, r+11, colB);
          rnb[ch] = (rnb[ch] << 4) | (u64)(nb & 15u);
          r16b[ch] = (r16b[ch] << 1) | (nb >> 4);
          u32 ob = (u32)((rnb[ch] >> 44) & 15u);
          u32 o16 = (r16b[ch] >> 11) & 1u;
          vb[ch] += bdelta(nb);
          vb[ch] -= o16 ? 0ull : (1ull << (ob*4));
          ulonglong2 e; e.x = vb[ch] & M4; e.y = (vb[ch] >> 4) & M4; CNT[ch][colB] = e;
        }
      }
      __syncthreads();
      #pragma unroll
      for (int ch=0; ch<3; ch++){
        ulonglong2 a = CNT[ch][t], b = CNT[ch][t+1];
        ulonglong2 p; p.x = a.x + b.x; p.y = a.y + b.y;
        P2S[ch][t] = p;
      }
      __syncthreads();
    }
  }
  for (int i=t; i<NTRIP; i+=512){ u32 c = lh[i]; if (c) atomicAdd(&hist[i], c); }
}

// ---- shared device helper: 9 integer moments + stage-1 folded P1 (all 256 threads) ----
__device__ __forceinline__ void compute_P1(const u32* __restrict__ hist,
    const void* w1, const void* b1, const void* wd1, const void* bd1,
    const void* g1, const void* be1, u32 f, float* sP /*LDS[128]*/,
    u32* wred /*LDS[36]*/, u32* mom /*LDS[9]*/){
  u32 a0=0,a1=0,a2=0,a3=0,a4=0,a5=0,a6=0,a7=0,a8=0;
  for (int t=threadIdx.x; t<NTRIP; t+=256){
    u32 c = hist[t];
    int m2 = t % 17; int tt = t/17; int m1 = tt % 17; int m0 = tt/17;
    a0 += c*m0; a1 += c*m1; a2 += c*m2;
    a3 += c*m0*m0; a4 += c*m1*m1; a5 += c*m2*m2;
    a6 += c*m0*m1; a7 += c*m0*m2; a8 += c*m1*m2;
  }
  #pragma unroll
  for (int s=1; s<64; s<<=1){
    a0 += __shfl_xor(a0,s); a1 += __shfl_xor(a1,s); a2 += __shfl_xor(a2,s);
    a3 += __shfl_xor(a3,s); a4 += __shfl_xor(a4,s); a5 += __shfl_xor(a5,s);
    a6 += __shfl_xor(a6,s); a7 += __shfl_xor(a7,s); a8 += __shfl_xor(a8,s);
  }
  int wv = threadIdx.x >> 6;
  if ((threadIdx.x & 63) == 0){
    wred[wv*9+0]=a0; wred[wv*9+1]=a1; wred[wv*9+2]=a2; wred[wv*9+3]=a3; wred[wv*9+4]=a4;
    wred[wv*9+5]=a5; wred[wv*9+6]=a6; wred[wv*9+7]=a7; wred[wv*9+8]=a8;
  }
  __syncthreads();
  if (threadIdx.x < 9) mom[threadIdx.x] = wred[threadIdx.x] + wred[9+threadIdx.x] + wred[18+threadIdx.x] + wred[27+threadIdx.x];
  __syncthreads();
  if (threadIdx.x < 32){
    int o = threadIdx.x;
    double wd = ldv(wd1,o,f);
    double q0 = wd*ldv(w1,o*3+0,f), q1 = wd*ldv(w1,o*3+1,f), q2 = wd*ldv(w1,o*3+2,f);
    double qc = wd*ldv(b1,o,f) + ldv(bd1,o,f);
    double S0=mom[0],S1=mom[1],S2=mom[2],S00=mom[3],S11=mom[4],S22=mom[5],S01=mom[6],S02=mom[7],S12=mom[8];
    double lin = (q0*S0 + q1*S1 + q2*S2) * (1.0/16.0);
    double mean = lin/N_F + qc;
    double quad = (q0*q0*S00 + q1*q1*S11 + q2*q2*S22 + 2.0*(q0*q1*S01 + q0*q2*S02 + q1*q2*S12)) * (1.0/256.0);
    double Ev2 = quad/N_F + 2.0*qc*lin/N_F + qc*qc;
    double var = Ev2 - mean*mean;
    double rstd = 1.0 / sqrt(var + 1e-5);
    double A = rstd * ldv(g1,o,f);
    double B = ldv(be1,o,f) - mean*A;
    sP[o]      = (float)(q0*A);
    sP[32+o]   = (float)(q1*A);
    sP[64+o]   = (float)(q2*A);
    sP[96+o]   = (float)(qc*A + B);
  }
  __syncthreads();
}

// ---------------- K2: triple-parallel pre-BN LUT + stage-2 BN sums ----------------
__global__ __launch_bounds__(256) void k_stats(const u32* __restrict__ hist,
    const void* w1, const void* b1, const void* wd1, const void* bd1, const void* g1, const void* be1,
    const void* w2, const void* b2, const void* wd2, const void* bd2,
    float* __restrict__ lutpre, double* __restrict__ sums2, const u32* __restrict__ flag){
  u32 f = *flag;
  __shared__ float sP[128];
  __shared__ u32 wred[36], mom[9];
  __shared__ float sw[1024];
  __shared__ float swd[32], scc[32];
  compute_P1(hist, w1,b1,wd1,bd1,g1,be1, f, sP, wred, mom);
  for (int i=threadIdx.x;i<1024;i+=256) sw[i] = ldv(w2, i, f);
  if (threadIdx.x < 32){
    int o = threadIdx.x;
    float wd = ldv(wd2,o,f);
    swd[o] = wd;
    scc[o] = wd*ldv(b2,o,f) + ldv(bd2,o,f);
  }
  __syncthreads();
  int o = threadIdx.x & 31, slot = threadIdx.x >> 5;
  double s = 0.0, q = 0.0;
  for (int t = blockIdx.x*8 + slot; t < NTRIP; t += gridDim.x*8){
    int m2 = t % 17; int tt = t/17; int m1 = tt % 17; int m0 = tt/17;
    float f0 = m0*(1.f/16.f), f1 = m1*(1.f/16.f), f2v = m2*(1.f/16.f);
    float dot = 0.f;
    #pragma unroll
    for (int c=0;c<32;c++){
      float u = sP[c]*f0 + sP[32+c]*f1 + sP[64+c]*f2v + sP[96+c];
      float y = (u >= 0.f) ? u : 0.01f*u;
      dot += sw[o*32+c]*y;
    }
    float v2 = swd[o]*dot + scc[o];
    lutpre[t*32+o] = v2;
    double cn = (double)hist[t];
    s += cn*(double)v2;
    q += cn*(double)v2*(double)v2;
  }
  s += __shfl_xor(s, 32);
  q += __shfl_xor(q, 32);
  __shared__ double sred[2][4][32];
  int wv = threadIdx.x >> 6, ln = threadIdx.x & 63;
  if (ln < 32){ sred[0][wv][ln] = s; sred[1][wv][ln] = q; }
  __syncthreads();
  if (threadIdx.x < 32){
    int oo = threadIdx.x;
    double ss = sred[0][0][oo]+sred[0][1][oo]+sred[0][2][oo]+sred[0][3][oo];
    atomicAdd(&sums2[oo], ss);
  } else if (threadIdx.x < 64){
    int oo = threadIdx.x - 32;
    double qq = sred[1][0][oo]+sred[1][1][oo]+sred[1][2][oo]+sred[1][3][oo];
    atomicAdd(&sums2[32+oo], qq);
  }
}

// ---------------- K3: gather pre-BN LUT -> BN affine + LeakyReLU -> output ----------------
__global__ __launch_bounds__(256) void k_out(const u16* __restrict__ triple, const float* __restrict__ lutpre,
                                             const double* __restrict__ sums2,
                                             const void* g2, const void* be2,
                                             void* __restrict__ out, const u32* __restrict__ flag){
  u32 f = *flag;
  __shared__ float ka[32], kb[32];
  if (threadIdx.x < 32){
    int o = threadIdx.x;
    double mean = sums2[o] / N_F;
    double var  = sums2[32+o] / N_F - mean*mean;
    double rstd = 1.0 / sqrt(var + 1e-5);
    double A = rstd * (double)ldv(g2,o,f);
    double B = (double)ldv(be2,o,f) - mean*A;
    ka[o] = (float)A; kb[o] = (float)B;
  }
  __syncthreads();
  int g = blockIdx.x*256 + threadIdx.x;
  if (g >= NPIX/2) return;
  int p0 = g*2;
  int bimg = p0 / PP; int pix = p0 - bimg*PP;
  u32 tt = *(const u32*)(triple + p0);
  u32 ia = tt & 0xFFFFu, ib = tt >> 16;
  const float4* La = (const float4*)(lutpre + (size_t)ia*32);
  const float4* Lb = (const float4*)(lutpre + (size_t)ib*32);
  if (f){  // float32 output path
    float* ob = (float*)out + (size_t)bimg*32*PP + pix;
    #pragma unroll
    for (int j=0;j<8;j++){
      float4 a = La[j]; float4 b = Lb[j];
      float4 K = *(const float4*)&ka[4*j];
      float4 C = *(const float4*)&kb[4*j];
      float2 v;
      float ax, bx;
      ax = fmaf(a.x, K.x, C.x); ax = ax>=0.f?ax:0.01f*ax;
      bx = fmaf(b.x, K.x, C.x); bx = bx>=0.f?bx:0.01f*bx;
      v.x=ax; v.y=bx; *(float2*)(ob + (size_t)(4*j+0)*PP) = v;
      ax = fmaf(a.y, K.y, C.y); ax = ax>=0.f?ax:0.01f*ax;
      bx = fmaf(b.y, K.y, C.y); bx = bx>=0.f?bx:0.01f*bx;
      v.x=ax; v.y=bx; *(float2*)(ob + (size_t)(4*j+1)*PP) = v;
      ax = fmaf(a.z, K.z, C.z); ax = ax>=0.f?ax:0.01f*ax;
      bx = fmaf(b.z, K.z, C.z); bx = bx>=0.f?bx:0.01f*bx;
      v.x=ax; v.y=bx; *(float2*)(ob + (size_t)(4*j+2)*PP) = v;
      ax = fmaf(a.w, K.w, C.w); ax = ax>=0.f?ax:0.01f*ax;
      bx = fmaf(b.w, K.w, C.w); bx = bx>=0.f?bx:0.01f*bx;
      v.x=ax; v.y=bx; *(float2*)(ob + (size_t)(4*j+3)*PP) = v;
    }
  } else { // bf16 output: apply affine+leaky then RNE-pack pixel pairs
    u16* ob = (u16*)out + (size_t)bimg*32*PP + pix;
    #pragma unroll
    for (int j=0;j<8;j++){
      float4 a = La[j]; float4 b = Lb[j];
      float4 K = *(const float4*)&ka[4*j];
      float4 C = *(const float4*)&kb[4*j];
      float ax, bx;
      ax = fmaf(a.x, K.x, C.x); ax = ax>=0.f?ax:0.01f*ax;
      bx = fmaf(b.x, K.x, C.x); bx = bx>=0.f?bx:0.01f*bx;
      *(u32*)(ob + (size_t)(4*j+0)*PP) = f2bf(ax) | (f2bf(bx) << 16);
      ax = fmaf(a.y, K.y, C.y); ax = ax>=0.f?ax:0.01f*ax;
      bx = fmaf(b.y, K.y, C.y); bx = bx>=0.f?bx:0.01f*bx;
      *(u32*)(ob + (size_t)(4*j+1)*PP) = f2bf(ax) | (f2bf(bx) << 16);
      ax = fmaf(a.z, K.z, C.z); ax = ax>=0.f?ax:0.01f*ax;
      bx = fmaf(b.z, K.z, C.z); bx = bx>=0.f?bx:0.01f*bx;
      *(u32*)(ob + (size_t)(4*j+2)*PP) = f2bf(ax) | (f2bf(bx) << 16);
      ax = fmaf(a.w, K.w, C.w); ax = ax>=0.f?ax:0.01f*ax;
      bx = fmaf(b.w, K.w, C.w); bx = bx>=0.f?bx:0.01f*bx;
      *(u32*)(ob + (size_t)(4*j+3)*PP) = f2bf(ax) | (f2bf(bx) << 16);
    }
  }
}

extern "C" void kernel_launch(void* const* d_in, const int* in_sizes, int n_in,
                              void* d_out, int out_size, void* d_ws, size_t ws_size,
                              hipStream_t stream){
  const void* x   = d_in[0];
  const void* w1  = d_in[1];
  const void* b1  = d_in[2];
  const void* wd1 = d_in[3];
  const void* bd1 = d_in[4];
  const void* g1  = d_in[5];
  const void* be1 = d_in[6];
  const void* w2  = d_in[7];
  const void* b2  = d_in[8];
  const void* wd2 = d_in[9];
  const void* bd2 = d_in[10];
  const void* g2  = d_in[11];
  const void* be2 = d_in[12];

  char* w = (char*)d_ws;
  auto alloc = [&](size_t bytes)->char* { char* p = w; w += (bytes + 255) & ~(size_t)255; return p; };
  u32*    flag   = (u32*)   alloc(256);
  u16*    triple = (u16*)   alloc(2ull*NPIX);        // 4.06 MB
  u32*    hist   = (u32*)   alloc(4ull*NTRIP);
  double* sums2  = (double*)alloc(64ull*8);
  float*  lutpre = (float*) alloc(4ull*NTRIP*32);    // 629 KB

  k_init<<<dim3(1), 256, 0, stream>>>((const u16*)x, flag, hist, (u32*)sums2);
  k_fused<<<dim3(NRB, 8), 512, 0, stream>>>(x, flag, triple, hist);
  k_stats<<<dim3(256), 256, 0, stream>>>(hist, w1,b1,wd1,bd1,g1,be1, w2,b2,wd2,bd2,
                                         lutpre, sums2, flag);
  k_out<<<dim3((NPIX/2)/256), 256, 0, stream>>>(triple, lutpre, sums2, g2, be2, d_out, flag);
}